// Round 7
// baseline (305.831 us; speedup 1.0000x reference)
//
#include <hip/hip_runtime.h>
#include <math.h>

#define HN 64
#define KNN 15

__device__ __forceinline__ unsigned fenc(float f){
  unsigned u = __float_as_uint(f);
  return (u & 0x80000000u) ? ~u : (u | 0x80000000u);
}

__device__ __forceinline__ unsigned long long u64min(unsigned long long a, unsigned long long b){
  return a < b ? a : b;
}
__device__ __forceinline__ unsigned long long shfl_xor_u64(unsigned long long v, int mask){
  unsigned lo = (unsigned)v, hi = (unsigned)(v >> 32);
  lo = __shfl_xor((int)lo, mask, 64);
  hi = __shfl_xor((int)hi, mask, 64);
  return ((unsigned long long)hi << 32) | lo;
}

// Per-wave int64-vs-int32 edge detection + read.
__device__ __forceinline__ void edge_load(const void* ei, int E, int n, int e, int& r, int& c){
  const long long* L = (const long long*)ei;
  long long vr = L[e];
  bool ok = (vr >= 0 && vr < (long long)n);
  unsigned long long bal = __ballot(ok);
  unsigned long long act = __ballot(true);
  if (bal == act){
    r = (int)vr;
    c = (int)L[E + e];
  } else {
    const int* I = (const int*)ei;
    r = I[e];
    c = I[E + e];
  }
}

// mega: [0,nbY) y = x@Wt^T ; [nbY,nbY+nbC) edge row/col counts ; rest kNN.
__global__ void __launch_bounds__(256) k_mega(
    const float* __restrict__ x, const float* __restrict__ Wt, const void* ei,
    float* __restrict__ y, int* __restrict__ knn_cols,
    int* __restrict__ cnt, int* __restrict__ ccnt,
    int N, int E, int nbY, int nbC){
  __shared__ unsigned denc[4096];
  __shared__ unsigned long long mk[256];
  int b = blockIdx.x, t = threadIdx.x;
  if (b < nbY){
    int gid = b * 256 + t;
    if (gid < N * HN){
      int nn = gid >> 6, h = gid & 63;
      y[gid] = x[nn*3] * Wt[h*3] + x[nn*3+1] * Wt[h*3+1] + x[nn*3+2] * Wt[h*3+2];
    }
    return;
  }
  if (b < nbY + nbC){
    int e = (b - nbY) * 256 + t;
    if (e < E){
      int r, c;
      edge_load(ei, E, N, e, r, c);
      atomicAdd(&cnt[r], 1);
      atomicAdd(&ccnt[c], 1);
    }
    return;
  }
  // ---- kNN for node i ----
  int i = b - nbY - nbC;
  float xi0 = x[i*3], xi1 = x[i*3+1], xi2 = x[i*3+2];
  float sqi = xi0*xi0 + xi1*xi1 + xi2*xi2;
  unsigned long long best = ~0ULL;
  #pragma unroll
  for (int m = 0; m < 16; ++m){
    int j = t + 256*m;
    float a = x[j*3], bb = x[j*3+1], c = x[j*3+2];
    float sqj = a*a + bb*bb + c*c;
    float dot = xi0*a + xi1*bb + xi2*c;
    float d2 = (sqi - 2.0f*dot) + sqj;
    unsigned e = (j == i) ? 0xFFFFFFFFu : fenc(d2);
    denc[j] = e;
    best = u64min(best, ((unsigned long long)e << 32) | (unsigned)j);
  }
  mk[t] = best;
  __syncthreads();
  if (t >= 64) return;
  unsigned long long k0 = mk[t], k1 = mk[t+64], k2 = mk[t+128], k3 = mk[t+192];
  for (int m = 0; m < KNN; ++m){
    unsigned long long mm = u64min(u64min(k0, k1), u64min(k2, k3));
    #pragma unroll
    for (int off = 1; off < 64; off <<= 1)
      mm = u64min(mm, shfl_xor_u64(mm, off));
    int j = (int)(mm & 0xFFFFFFFFu);
    if (t == 0) knn_cols[i*KNN + m] = j;
    if ((j & 63) == t){
      int slot = j & 255;
      denc[j] = 0xFFFFFFFFu;
      unsigned long long nb = ~0ULL;
      #pragma unroll
      for (int m2 = 0; m2 < 16; ++m2){
        int jj = slot + 256*m2;
        nb = u64min(nb, ((unsigned long long)denc[jj] << 32) | (unsigned)jj);
      }
      int kreg = (j >> 6) & 3;
      if (kreg == 0) k0 = nb; else if (kreg == 1) k1 = nb;
      else if (kreg == 2) k2 = nb; else k3 = nb;
    }
  }
}

// two exclusive scans in one launch; also emits packed (base,len) info tables:
// rinfo[k] = (ptr[k]+KNN*k, cnt[k])   cinfo[l] = (cptr[l], ccnt[l])
__global__ void k_scan2(const int* __restrict__ cnt, int* __restrict__ ptr,
                        const int* __restrict__ ccnt, int* __restrict__ cptr,
                        int2* __restrict__ rinfo, int2* __restrict__ cinfo, int n){
  __shared__ int part[1024];
  const int* src = (blockIdx.x == 0) ? cnt : ccnt;
  int* dst = (blockIdx.x == 0) ? ptr : cptr;
  int t = threadIdx.x;
  int base = t * 4;
  int a0 = src[base], a1 = src[base+1], a2 = src[base+2], a3 = src[base+3];
  int s = a0 + a1 + a2 + a3;
  part[t] = s;
  __syncthreads();
  for (int off = 1; off < 1024; off <<= 1){
    int v = (t >= off) ? part[t - off] : 0;
    __syncthreads();
    part[t] += v;
    __syncthreads();
  }
  int excl = part[t] - s;
  int v0 = excl, v1 = excl + a0, v2 = excl + a0 + a1, v3 = excl + a0 + a1 + a2;
  dst[base]   = v0;
  dst[base+1] = v1;
  dst[base+2] = v2;
  dst[base+3] = v3;
  if (t == 1023) dst[n] = part[1023];
  if (blockIdx.x == 0){
    rinfo[base]   = make_int2(v0 + KNN*base,     a0);
    rinfo[base+1] = make_int2(v1 + KNN*(base+1), a1);
    rinfo[base+2] = make_int2(v2 + KNN*(base+2), a2);
    rinfo[base+3] = make_int2(v3 + KNN*(base+3), a3);
  } else {
    cinfo[base]   = make_int2(v0, a0);
    cinfo[base+1] = make_int2(v1, a1);
    cinfo[base+2] = make_int2(v2, a2);
    cinfo[base+3] = make_int2(v3, a3);
  }
}

// fused extended-CSR fill: originals (atomic slots) + knn (deterministic slots)
__global__ void k_fill(const void* ei, const int* __restrict__ ptr,
                       int* __restrict__ fillo, const int* __restrict__ cnt,
                       const int* __restrict__ knncols, int* __restrict__ ecol,
                       int N, int E, int nbE){
  int b = blockIdx.x, t = threadIdx.x;
  if (b < nbE){
    int e = b * 256 + t;
    if (e < E){
      int r, c;
      edge_load(ei, E, N, e, r, c);
      int pos = ptr[r] + KNN*r + atomicAdd(&fillo[r], 1);
      ecol[pos] = c;
    }
  } else {
    int gid = (b - nbE) * 256 + t;
    if (gid < N * KNN){
      int i = gid / KNN, m = gid - i * KNN;
      ecol[ptr[i] + KNN*i + cnt[i] + m] = knncols[gid];
    }
  }
}

// fused DevConv-min + feats + q/k projections (agg/feats live in LDS only)
__global__ void k_dev(const int* __restrict__ ptr, const int* __restrict__ ecol,
                      const float* __restrict__ y, const float* __restrict__ bt,
                      const float* __restrict__ Wp, const float* __restrict__ bp,
                      const float* __restrict__ Wq, const float* __restrict__ Wk,
                      float* __restrict__ q, float* __restrict__ kf, int n){
  __shared__ float sag[256];
  __shared__ float sft[256];
  int t = threadIdx.x;
  int i = blockIdx.x * 4 + (t >> 6);
  int h = t & 63;
  int beg = ptr[i] + KNN*i;
  int end = ptr[i+1] + KNN*(i+1);
  float m = INFINITY;
  for (int idx = beg; idx < end; ++idx)
    m = fminf(m, y[ecol[idx]*HN + h]);
  sag[t] = y[i*HN + h] + bt[h] - m;
  __syncthreads();
  int nn = t >> 6;
  float acc = bp[h];
  #pragma unroll 8
  for (int c = 0; c < HN; ++c) acc += sag[nn*HN + c] * Wp[h*HN + c];
  sft[t] = acc;
  __syncthreads();
  float aq = 0.f, ak = 0.f;
  #pragma unroll 8
  for (int c = 0; c < HN; ++c){
    float f = sft[nn*HN + c];
    aq += f * Wq[h*HN + c];
    ak += f * Wk[h*HN + c];
  }
  size_t o = (size_t)blockIdx.x * 256 + t;
  q[o] = aq;
  kf[o] = ak;
}

// row-centric attention, lane-parallel over edges. Writes scp (col,val) CSR-order,
// csp (row,val) CSC-order, and tlen[r] = sum of indeg over A-row r (free: cinfo loaded anyway).
__global__ void __launch_bounds__(256) k_rowattn(
    const int* __restrict__ ptr, const int2* __restrict__ cinfo,
    const int* __restrict__ ecol, const float* __restrict__ q,
    const float* __restrict__ kf, float* __restrict__ sval,
    int2* __restrict__ scp, int2* __restrict__ csp,
    int* __restrict__ cfill, int* __restrict__ tlen, int n){
  int t = threadIdx.x;
  int lane = t & 63;
  int r = blockIdx.x * 4 + (t >> 6);
  if (r >= n) return;
  int base = ptr[r];
  int deg = ptr[r+1] - base;
  if (deg == 0) return;
  int ebase = base + KNN*r;
  float4 qv[16];
  const float4* qr = (const float4*)(q + (size_t)r*HN);
  #pragma unroll
  for (int m = 0; m < 16; ++m) qv[m] = qr[m];
  float mx = -INFINITY;
  for (int s = lane; s < deg; s += 64){
    int c = ecol[ebase + s];
    const float4* kc = (const float4*)(kf + (size_t)c*HN);
    float acc = 0.f;
    #pragma unroll
    for (int m = 0; m < 16; ++m){
      float4 b = kc[m];
      acc += qv[m].x*b.x + qv[m].y*b.y + qv[m].z*b.z + qv[m].w*b.w;
    }
    sval[base + s] = acc;
    mx = fmaxf(mx, acc);
  }
  #pragma unroll
  for (int off = 1; off < 64; off <<= 1) mx = fmaxf(mx, __shfl_xor(mx, off, 64));
  float lsum = 0.f;
  for (int s = lane; s < deg; s += 64){
    float e = expf(sval[base + s] - mx);
    sval[base + s] = e;
    lsum += e;
  }
  #pragma unroll
  for (int off = 1; off < 64; off <<= 1) lsum += __shfl_xor(lsum, off, 64);
  int tsum = 0;
  for (int s = lane; s < deg; s += 64){
    float v = sval[base + s] / lsum;
    int c = ecol[ebase + s];
    scp[base + s] = make_int2(c, __float_as_int(v));
    int2 ci = cinfo[c];
    int pos = ci.x + atomicAdd(&cfill[c], 1);
    csp[pos] = make_int2(r, __float_as_int(v));
    tsum += ci.y;
  }
  #pragma unroll
  for (int off = 1; off < 64; off <<= 1) tsum += __shfl_xor(tsum, off, 64);
  if (lane == 0) tlen[r] = tsum;
}

// exclusive scan over tlen -> tinfo[k] = (offset, len)
__global__ void k_scant(const int* __restrict__ tlen, int2* __restrict__ tinfo, int n){
  __shared__ int part[1024];
  int t = threadIdx.x;
  int base = t * 4;
  int a0 = tlen[base], a1 = tlen[base+1], a2 = tlen[base+2], a3 = tlen[base+3];
  int s = a0 + a1 + a2 + a3;
  part[t] = s;
  __syncthreads();
  for (int off = 1; off < 1024; off <<= 1){
    int v = (t >= off) ? part[t - off] : 0;
    __syncthreads();
    part[t] += v;
    __syncthreads();
  }
  int excl = part[t] - s;
  tinfo[base]   = make_int2(excl, a0);
  tinfo[base+1] = make_int2(excl + a0, a1);
  tinfo[base+2] = make_int2(excl + a0 + a1, a2);
  tinfo[base+3] = make_int2(excl + a0 + a1 + a2, a3);
}

// T-row k = concat over l in A-row(k) of csp-segment(l). Pure segment copy.
__global__ void __launch_bounds__(256) k_tbuild(
    const int2* __restrict__ rinfo, const int* __restrict__ ecol,
    const int2* __restrict__ cinfo, const int2* __restrict__ csp,
    const int2* __restrict__ tinfo, int2* __restrict__ tlist, int n){
  __shared__ int pre[65];
  __shared__ int csrc[64];
  int k = blockIdx.x, t = threadIdx.x, lane = t & 63;
  int2 ri = rinfo[k];
  int running = tinfo[k].x;
  for (int l0 = 0; l0 < ri.y; l0 += 64){
    int chunk = min(64, ri.y - l0);
    __syncthreads();
    if (t < 64){
      int v = 0, src = 0;
      if (lane < chunk){
        int c = ecol[ri.x + l0 + lane];
        int2 ci = cinfo[c];
        v = ci.y; src = ci.x;
      }
      csrc[lane] = src;
      int ps = v;
      #pragma unroll
      for (int off = 1; off < 64; off <<= 1){
        int o = __shfl_up(ps, off, 64);
        if (lane >= off) ps += o;
      }
      pre[lane + 1] = ps;
      if (lane == 0) pre[0] = 0;
    }
    __syncthreads();
    int total = pre[chunk];
    for (int d = t; d < total; d += 256){
      int lo = 0, hi = chunk - 1;
      while (lo < hi){
        int mid = (lo + hi + 1) >> 1;
        if (pre[mid] <= d) lo = mid; else hi = mid - 1;
      }
      tlist[running + d] = csp[csrc[lo] + (d - pre[lo])];
    }
    running += total;
  }
}

// A_s row i = sum_p v_p * T-row(k_p): contiguous streams into LDS dense row.
__global__ void __launch_bounds__(256) k_papply(
    const int* __restrict__ ptr, const int2* __restrict__ scp,
    const int2* __restrict__ tinfo, const int2* __restrict__ tlist,
    float* __restrict__ out, int n){
  __shared__ float orow[4096];
  __shared__ float svv[64];
  __shared__ int2  sti[64];
  int i = blockIdx.x, t = threadIdx.x;
  float4 z = {0.f, 0.f, 0.f, 0.f};
  float4* o4 = (float4*)orow;
  #pragma unroll
  for (int ch = 0; ch < 4; ++ch) o4[ch*256 + t] = z;
  int base = ptr[i];
  int len = ptr[i+1] - base;
  for (int p0 = 0; p0 < len; p0 += 64){
    int chunk = min(64, len - p0);
    __syncthreads();               // orow zeroed / svv reuse safe
    if (t < chunk){
      int2 kv = scp[base + p0 + t];
      svv[t] = __int_as_float(kv.y);
      sti[t] = tinfo[kv.x];
    }
    __syncthreads();
    for (int p = 0; p < chunk; ++p){
      float v = svv[p];
      int2 ti = sti[p];
      for (int d = t; d < ti.y; d += 256){
        int2 e = tlist[ti.x + d];
        atomicAdd(&orow[e.x], v * __int_as_float(e.y));
      }
    }
  }
  __syncthreads();
  float4* dst = (float4*)(out + (size_t)i * n);
  #pragma unroll
  for (int ch = 0; ch < 4; ++ch) dst[ch*256 + t] = o4[ch*256 + t];
}

extern "C" void kernel_launch(void* const* d_in, const int* in_sizes, int n_in,
                              void* d_out, int out_size, void* d_ws, size_t ws_size,
                              hipStream_t stream) {
  const float* x   = (const float*)d_in[0];
  const void*  ei  = d_in[1];
  const float* Wt  = (const float*)d_in[2];
  const float* bt  = (const float*)d_in[3];
  const float* Wp  = (const float*)d_in[4];
  const float* bp  = (const float*)d_in[5];
  const float* Wq  = (const float*)d_in[6];
  const float* Wk  = (const float*)d_in[7];
  float* out = (float*)d_out;

  const int N = in_sizes[0] / 3;         // 4096
  const int E = in_sizes[1] / 2;         // 65536

  char* p = (char*)d_ws;
  auto alloc = [&](size_t bytes) -> void* {
    void* r = (void*)p;
    p += (bytes + 255) & ~(size_t)255;
    return r;
  };
  int*      ctr     = (int*)  alloc((size_t)5*N*4);   // cnt, ccnt, cfill, fillo, tlen
  int*      cnt     = ctr;
  int*      ccnt    = ctr + N;
  int*      cfill   = ctr + 2*N;
  int*      fillo   = ctr + 3*N;
  int*      tlen    = ctr + 4*N;

  float*    y       = (float*)alloc((size_t)N*HN*4);
  float*    q       = (float*)alloc((size_t)N*HN*4);
  float*    kf      = (float*)alloc((size_t)N*HN*4);
  int*      ptrb    = (int*)  alloc((size_t)(N+1)*4);
  int*      cptrb   = (int*)  alloc((size_t)(N+1)*4);
  int2*     rinfo   = (int2*) alloc((size_t)N*8);
  int2*     cinfo   = (int2*) alloc((size_t)N*8);
  int2*     tinfo   = (int2*) alloc((size_t)N*8);
  int*      ecol    = (int*)  alloc((size_t)(E + N*KNN)*4);
  float*    sval    = (float*)alloc((size_t)E*4);
  int2*     scp     = (int2*) alloc((size_t)E*8);
  int2*     csp     = (int2*) alloc((size_t)E*8);
  int*      knncols = (int*)  alloc((size_t)N*KNN*4);
  int2*     tlist   = (int2*) alloc((size_t)4*1024*1024*8);  // 32MB, exp ~9MB

  hipMemsetAsync(ctr, 0, (size_t)5*N*4, stream);

  int nbY = (N*HN + 255)/256;            // 1024
  int nbC = (E + 255)/256;               // 256
  int nbK = (N*KNN + 255)/256;           // 240

  k_mega<<<nbY + nbC + N, 256, 0, stream>>>(x, Wt, ei, y, knncols, cnt, ccnt,
                                            N, E, nbY, nbC);
  k_scan2<<<2, 1024, 0, stream>>>(cnt, ptrb, ccnt, cptrb, rinfo, cinfo, N);
  k_fill<<<nbC + nbK, 256, 0, stream>>>(ei, ptrb, fillo, cnt, knncols, ecol,
                                        N, E, nbC);
  k_dev<<<N/4, 256, 0, stream>>>(ptrb, ecol, y, bt, Wp, bp, Wq, Wk, q, kf, N);
  k_rowattn<<<N/4, 256, 0, stream>>>(ptrb, cinfo, ecol, q, kf, sval, scp, csp,
                                     cfill, tlen, N);
  k_scant<<<1, 1024, 0, stream>>>(tlen, tinfo, N);
  k_tbuild<<<N, 256, 0, stream>>>(rinfo, ecol, cinfo, csp, tinfo, tlist, N);
  k_papply<<<N, 256, 0, stream>>>(ptrb, scp, tinfo, tlist, out, N);
}